// Round 6
// baseline (427.989 us; speedup 1.0000x reference)
//
#include <hip/hip_runtime.h>
#include <math.h>

// Problem constants
#define BATCH  4
#define LSEQ   2048
#define DMODEL 1024
#define MROWS  (BATCH * LSEQ)   // 8192
#define SCORE_SCALE 8.0f        // sqrt(1024/16), reference MULTIPLIES

#define THREEFRY_PARTITIONABLE 1  // verified correct in round 1

typedef __bf16 bf16_t;
typedef bf16_t bf16x8 __attribute__((ext_vector_type(8)));
typedef bf16_t bf16x4 __attribute__((ext_vector_type(4)));
typedef float  f32x4  __attribute__((ext_vector_type(4)));

#define LDSP(p) ((__attribute__((address_space(3))) void*)(p))
#define GLBP(p) ((const __attribute__((address_space(1))) void*)(p))

// ---------------------------------------------------------------------------
// threefry dropout (verified round 1; mask MUST match reference — near-one-hot
// softmax means a flipped keep-bit on the dominant prob changes output by ~2|V|)
// ---------------------------------------------------------------------------
__device__ __forceinline__ unsigned rotl32(unsigned x, int r) {
    return (x << r) | (x >> (32 - r));
}

__device__ __forceinline__ void threefry2x32(unsigned k0, unsigned k1,
                                             unsigned x0, unsigned x1,
                                             unsigned& o0, unsigned& o1) {
    const unsigned ks0 = k0, ks1 = k1, ks2 = k0 ^ k1 ^ 0x1BD11BDAu;
    x0 += ks0; x1 += ks1;
#define TF_R(r) { x0 += x1; x1 = rotl32(x1, r); x1 ^= x0; }
    TF_R(13) TF_R(15) TF_R(26) TF_R(6)
    x0 += ks1; x1 += ks2 + 1u;
    TF_R(17) TF_R(29) TF_R(16) TF_R(24)
    x0 += ks2; x1 += ks0 + 2u;
    TF_R(13) TF_R(15) TF_R(26) TF_R(6)
    x0 += ks0; x1 += ks1 + 3u;
    TF_R(17) TF_R(29) TF_R(16) TF_R(24)
    x0 += ks1; x1 += ks2 + 4u;
    TF_R(13) TF_R(15) TF_R(26) TF_R(6)
    x0 += ks2; x1 += ks0 + 5u;
#undef TF_R
    o0 = x0; o1 = x1;
}

__device__ __forceinline__ bool dropout_keep(unsigned n) {
    unsigned o0, o1;
#if THREEFRY_PARTITIONABLE
    threefry2x32(0u, 42u, 0u, n, o0, o1);
    unsigned bits = o0 ^ o1;
#else
    const unsigned HALF = (unsigned)(BATCH * LSEQ) * (unsigned)LSEQ / 2u;
    unsigned c0 = (n < HALF) ? n : (n - HALF);
    unsigned c1 = (n < HALF) ? (n + HALF) : n;
    threefry2x32(0u, 42u, c0, c1, o0, o1);
    unsigned bits = (n < HALF) ? o0 : o1;
#endif
    return bits < 0x80000000u;
}

// ---------------------------------------------------------------------------
// r11: merged prep kernels.
// split_all: y0=query,y1=key -> hi/lo planes; y2=value -> hi only.
// ---------------------------------------------------------------------------
__global__ __launch_bounds__(256)
void split_all(const float* __restrict__ Xq, const float* __restrict__ Xk,
               const float* __restrict__ Xv,
               bf16_t* __restrict__ hi, bf16_t* __restrict__ lo,
               bf16_t* __restrict__ vh, int n) {
    const int y = blockIdx.y;
    const float* X = (y == 0) ? Xq : (y == 1) ? Xk : Xv;
    long long i = (long long)(blockIdx.x * 256 + threadIdx.x) * 4;
    if (i >= n) return;
    float4 v = *(const float4*)(X + i);
    bf16x4 h, l;
    h[0] = (bf16_t)v.x; l[0] = (bf16_t)(v.x - (float)h[0]);
    h[1] = (bf16_t)v.y; l[1] = (bf16_t)(v.y - (float)h[1]);
    h[2] = (bf16_t)v.z; l[2] = (bf16_t)(v.z - (float)h[2]);
    h[3] = (bf16_t)v.w; l[3] = (bf16_t)(v.w - (float)h[3]);
    if (y < 2) {
        *(bf16x4*)(hi + (long long)y * n + i) = h;
        *(bf16x4*)(lo + (long long)y * n + i) = l;
    } else {
        *(bf16x4*)(vh + i) = h;
    }
}

// W fp32 [K][N] -> W^T hi/lo bf16 [N][K]; z: 0=Wq,1=Wk (2-slot out), 2=Wv (own out)
__global__ __launch_bounds__(256)
void split_transpose3(const float* __restrict__ W0, const float* __restrict__ W1,
                      const float* __restrict__ W2,
                      bf16_t* __restrict__ Th01, bf16_t* __restrict__ Tl01,
                      bf16_t* __restrict__ Thv, bf16_t* __restrict__ Tlv,
                      int Kd, int Nd) {
    __shared__ float t[32][33];
    const int z = blockIdx.z;
    const float* W = (z == 0) ? W0 : (z == 1) ? W1 : W2;
    bf16_t* Th = (z == 2) ? Thv : Th01 + (long long)z * Kd * Nd;
    bf16_t* Tl = (z == 2) ? Tlv : Tl01 + (long long)z * Kd * Nd;
    const int bx = blockIdx.x * 32;  // n
    const int by = blockIdx.y * 32;  // k
    const int tx = threadIdx.x & 31, ty = threadIdx.x >> 5;  // 32x8
#pragma unroll
    for (int i = 0; i < 4; ++i)
        t[ty + i * 8][tx] = W[(long long)(by + ty + i * 8) * Nd + bx + tx];
    __syncthreads();
#pragma unroll
    for (int i = 0; i < 4; ++i) {
        float v = t[tx][ty + i * 8];
        long long idx = (long long)(bx + ty + i * 8) * Kd + by + tx;
        bf16_t h = (bf16_t)v;
        Th[idx] = h;
        Tl[idx] = (bf16_t)(v - (float)h);
    }
}

// ---------------------------------------------------------------------------
// r10 gemm_pipe + r11 LDS-bounce epilogue (full-line coalesced stores).
// K-loop identical to r10 (verified). Epilogue: per-wave private 16x64 f32
// strip in LDS (swizzle col' = col ^ (row<<2)), read back row-major float4 ->
// 256B (fp32) / 128B (bf16) contiguous segments. Pre-bounce s_barrier makes
// strip reuse of tile buffers safe vs wave skew (NIT%3-dependent live buffer).
// ---------------------------------------------------------------------------
template <int OUT>
__global__ __launch_bounds__(512, 2)
void gemm_pipe(const bf16_t* __restrict__ A, const bf16_t* __restrict__ B,
               const float* __restrict__ bias,
               float* __restrict__ Cf, bf16_t* __restrict__ Ch,
               int M, int N, int K, float scale,
               long long sA, long long sB, long long sC,
               int NYt, int NZ) {
    constexpr int ABUF = 128 * 32;                 // A plane elements (8 KB)
    constexpr int BUFE = ABUF + 256 * 32;          // one buffer = 24 KB
    __shared__ __align__(16) bf16_t smem[3 * BUFE];  // 72 KB

    const int bid = blockIdx.x;
    const int gid = (bid & 7) * 32 + (bid >> 3);   // 256 blocks
    const int nzy = NZ * NYt;
    const int nx = gid / nzy;
    const int rem = gid - nx * nzy;
    const int zz = rem / NYt;
    const int my = rem - zz * NYt;
    const long long z = zz;
    const int m0 = my * 128, n0 = nx * 256;

    const int tid = threadIdx.x;
    const int lane = tid & 63;
    const int wave = tid >> 6;          // 0..7
    const int quad = lane >> 4;
    const int l16 = lane & 15;
    const int wm = (wave >> 2) * 64;    // 0,64
    const int wn = (wave & 3) * 64;     // 0,64,128,192

    const bf16_t* gA = A + z * sA;
    const bf16_t* gB = B + z * sB;

    const int lrow = lane >> 2;                               // 0..15
    const int scol = ((lane & 3) ^ ((lrow >> 1) & 3)) * 8;    // swizzled col
    const int sw = (l16 >> 1) & 3;                            // read swizzle

    auto stage_tile = [&](int k0, bf16_t* base) {
        {
            const int row = (wave << 4) + lrow;
            __builtin_amdgcn_global_load_lds(
                GLBP(gA + (long long)(m0 + row) * K + k0 + scol),
                LDSP(base + row * 32), 16, 0, 0);
        }
#pragma unroll
        for (int r = 0; r < 2; ++r) {
            const int row = (r << 7) + (wave << 4) + lrow;
            __builtin_amdgcn_global_load_lds(
                GLBP(gB + (long long)(n0 + row) * K + k0 + scol),
                LDSP(base + ABUF + row * 32), 16, 0, 0);
        }
    };

    f32x4 acc[4][4];
#pragma unroll
    for (int i = 0; i < 4; ++i)
#pragma unroll
        for (int j = 0; j < 4; ++j)
            acc[i][j] = (f32x4){0.f, 0.f, 0.f, 0.f};

    bf16x8 fa0[4], fb0[4], fa1[4], fb1[4];

    const int NIT = K >> 5;

    bf16_t* p0 = smem;
    bf16_t* p1 = smem + BUFE;
    bf16_t* p2 = smem + 2 * BUFE;

    stage_tile(0, p0);
    stage_tile(32, p1);
    stage_tile(64, p2);
    asm volatile("s_waitcnt vmcnt(3)" ::: "memory");
    asm volatile("s_barrier" ::: "memory");
    __builtin_amdgcn_sched_barrier(0);
#pragma unroll
    for (int i = 0; i < 4; ++i) {
        const int ao = (wm + i * 16 + l16) * 32 + (quad ^ sw) * 8;
        fa0[i] = *(const bf16x8*)(p0 + ao);
    }
#pragma unroll
    for (int j = 0; j < 4; ++j) {
        const int bo = ABUF + (wn + j * 16 + l16) * 32 + (quad ^ sw) * 8;
        fb0[j] = *(const bf16x8*)(p0 + bo);
    }

#define PIPE_ITER(T, FAc, FBc, FAn, FBn)                                      \
    {                                                                         \
        const int t_ = (T);                                                   \
        if (t_ + 1 < NIT) {                                                   \
            _Pragma("unroll")                                                 \
            for (int i = 0; i < 4; ++i) {                                     \
                const int ao = (wm + i * 16 + l16) * 32 + (quad ^ sw) * 8;    \
                FAn[i] = *(const bf16x8*)(p1 + ao);                           \
            }                                                                 \
            _Pragma("unroll")                                                 \
            for (int j = 0; j < 4; ++j) {                                     \
                const int bo = ABUF + (wn + j * 16 + l16) * 32 + (quad ^ sw) * 8; \
                FBn[j] = *(const bf16x8*)(p1 + bo);                           \
            }                                                                 \
        }                                                                     \
        if (t_ + 3 < NIT) stage_tile((t_ + 3) << 5, p0);                      \
        __builtin_amdgcn_s_setprio(1);                                        \
        _Pragma("unroll")                                                     \
        for (int i = 0; i < 4; ++i)                                           \
            _Pragma("unroll")                                                 \
            for (int j = 0; j < 4; ++j)                                       \
                acc[i][j] = __builtin_amdgcn_mfma_f32_16x16x32_bf16(          \
                    FAc[i], FBc[j], acc[i][j], 0, 0, 0);                      \
        __builtin_amdgcn_s_setprio(0);                                        \
        if (t_ + 2 < NIT) {                                                   \
            asm volatile("s_waitcnt lgkmcnt(0)" ::: "memory");                \
            if (t_ + 3 < NIT) asm volatile("s_waitcnt vmcnt(3)" ::: "memory");\
            else              asm volatile("s_waitcnt vmcnt(0)" ::: "memory");\
            asm volatile("s_barrier" ::: "memory");                           \
            __builtin_amdgcn_sched_barrier(0);                                \
        }                                                                     \
        { bf16_t* tmp_ = p0; p0 = p1; p1 = p2; p2 = tmp_; }                   \
    }

    for (int tp = 0; tp < NIT; tp += 2) {
        PIPE_ITER(tp,     fa0, fb0, fa1, fb1)
        PIPE_ITER(tp + 1, fa1, fb1, fa0, fb0)
    }
#undef PIPE_ITER

    // --- r11 LDS-bounce epilogue ---
    asm volatile("s_barrier" ::: "memory");   // all waves done with tile bufs
    float* strip = (float*)smem + wave * 1024;  // 16x64 f32 private strip
#pragma unroll
    for (int i = 0; i < 4; ++i) {
#pragma unroll
        for (int j = 0; j < 4; ++j)
#pragma unroll
            for (int r = 0; r < 4; ++r) {
                const int row = quad * 4 + r;
                const int col = j * 16 + l16;
                strip[row * 64 + (col ^ (row << 2))] = acc[i][j][r];
            }
        asm volatile("s_waitcnt lgkmcnt(0)" ::: "memory");
        __builtin_amdgcn_sched_barrier(0);
#pragma unroll
        for (int k = 0; k < 4; ++k) {
            const int R = k * 4 + (lane >> 4);
            const int c = (lane & 15) * 4;
            f32x4 v = *(const f32x4*)(strip + R * 64 + (c ^ (R << 2)));
            const int grow = m0 + wm + i * 16 + R;
            const int gcol = n0 + wn + c;
            const long long idx = z * sC + (long long)grow * N + gcol;
            if constexpr (OUT == 0) {
                v *= scale;
                *(f32x4*)(Cf + idx) = v;
            } else {
                const float bm = bias[grow];
                v += bm;
                bf16x4 h4;
                h4[0] = (bf16_t)v[0]; h4[1] = (bf16_t)v[1];
                h4[2] = (bf16_t)v[2]; h4[3] = (bf16_t)v[3];
                *(bf16x4*)(Ch + idx) = h4;
            }
        }
        asm volatile("s_waitcnt lgkmcnt(0)" ::: "memory");
        __builtin_amdgcn_sched_barrier(0);
    }
}

// ---------------------------------------------------------------------------
// r9 split kernel K-loop (frozen, verified 94.8us) + r11 LDS-bounce epilogue.
// ---------------------------------------------------------------------------
template <int OUT>
__global__ __launch_bounds__(512, 2)
void gemm_mfma_8ph(const bf16_t* __restrict__ Ah, const bf16_t* __restrict__ Al,
                   const bf16_t* __restrict__ Bh, const bf16_t* __restrict__ Bl,
                   const float* __restrict__ bias, const float* __restrict__ bias2,
                   float* __restrict__ Cf, bf16_t* __restrict__ Ch,
                   bf16_t* __restrict__ Cl,
                   int M, int N, int K, float scale,
                   long long sA, long long sB, long long sC,
                   int NYt, int NZ) {
    constexpr int TM = 256, TN = 256;
    constexpr int PLANE = 256 * 32;               // elements per plane (16 KB)
    constexpr int HB = 4 * PLANE;                 // half (one buffer) = 64 KB
    __shared__ __align__(16) bf16_t smem[2 * HB]; // 128 KB

    const int bid = blockIdx.x;
    const int gid = (bid & 7) * 32 + (bid >> 3);   // 256 blocks total
    const int nzy = NZ * NYt;
    const int nx = gid / nzy;
    const int rem = gid - nx * nzy;
    const int zz = rem / NYt;
    const int my = rem - zz * NYt;
    const long long z = zz;
    const int m0 = my * TM, n0 = nx * TN;

    const int tid = threadIdx.x;
    const int lane = tid & 63;
    const int wave = tid >> 6;          // 0..7
    const int quad = lane >> 4;
    const int l16 = lane & 15;
    const int wm = (wave >> 2) * 128;   // 0,128
    const int wn = (wave & 3) * 64;     // 0,64,128,192

    const bf16_t* gAh = Ah + z * sA;
    const bf16_t* gAl = Al + z * sA;
    const bf16_t* gBh = Bh + z * sB;
    const bf16_t* gBl = Bl + z * sB;

    const int lrow = lane >> 2;                               // 0..15
    const int scol = ((lane & 3) ^ ((lrow >> 1) & 3)) * 8;    // swizzled col
    const int sw = (l16 >> 1) & 3;                            // read swizzle

    auto stage_round = [&](int r, int k0, bf16_t* base) {
        if (r < 4) {
            const int row = ((r & 1) << 7) + (wave << 4) + lrow;
            const bf16_t* src = (r >= 2) ? gBl : gBh;
            bf16_t* dst = base + ((r >= 2) ? 3 : 2) * PLANE + row * 32;
            __builtin_amdgcn_global_load_lds(
                GLBP(src + (long long)(n0 + row) * K + k0 + scol), LDSP(dst), 16, 0, 0);
        } else {
            const int p = r - 4;
            const int row = (p << 5) + ((wave & 2) ? 128 : 0) + ((wave & 1) << 4) + lrow;
            const bf16_t* src = (wave >= 4) ? gAl : gAh;
            bf16_t* dst = base + ((wave >= 4) ? 1 : 0) * PLANE + row * 32;
            __builtin_amdgcn_global_load_lds(
                GLBP(src + (long long)(m0 + row) * K + k0 + scol), LDSP(dst), 16, 0, 0);
        }
    };

    f32x4 acc[8][4];
#pragma unroll
    for (int i = 0; i < 8; ++i)
#pragma unroll
        for (int j = 0; j < 4; ++j)
            acc[i][j] = (f32x4){0.f, 0.f, 0.f, 0.f};

    bf16x8 ah[2][2], al[2][2];
    bf16x8 bfh[4], bfl[4];

#pragma unroll
    for (int r = 0; r < 8; ++r) stage_round(r, 0, smem);
    asm volatile("s_waitcnt vmcnt(2)" ::: "memory");
    asm volatile("s_barrier" ::: "memory");
    __builtin_amdgcn_sched_barrier(0);
#pragma unroll
    for (int i = 0; i < 2; ++i) {
        const int ao = (wm + i * 16 + l16) * 32 + (quad ^ sw) * 8;
        ah[0][i] = *(const bf16x8*)(smem + ao);
        al[0][i] = *(const bf16x8*)(smem + PLANE + ao);
    }
#pragma unroll
    for (int j = 0; j < 4; ++j) {
        const int bo = (wn + j * 16 + l16) * 32 + (quad ^ sw) * 8;
        bfh[j] = *(const bf16x8*)(smem + 2 * PLANE + bo);
        bfl[j] = *(const bf16x8*)(smem + 3 * PLANE + bo);
    }

    const int NIT = K >> 5;   // 32 (even)
    for (int itp = 0; itp < NIT; itp += 2) {
#pragma unroll
        for (int h = 0; h < 2; ++h) {
            const int it = itp + h;
            const bool more = (it + 1) < NIT;
            const int k1 = (it + 1) << 5;
            bf16_t* cur = smem + h * HB;
            bf16_t* nxt = smem + (h ^ 1) * HB;
#pragma unroll
            for (int ph = 0; ph < 4; ++ph) {
                if (ph < 3) {
#pragma unroll
                    for (int i = 0; i < 2; ++i) {
                        const int ao = (wm + ((ph + 1) * 2 + i) * 16 + l16) * 32 + (quad ^ sw) * 8;
                        ah[(ph + 1) & 1][i] = *(const bf16x8*)(cur + ao);
                        al[(ph + 1) & 1][i] = *(const bf16x8*)(cur + PLANE + ao);
                    }
                } else if (more) {
#pragma unroll
                    for (int i = 0; i < 2; ++i) {
                        const int ao = (wm + i * 16 + l16) * 32 + (quad ^ sw) * 8;
                        ah[0][i] = *(const bf16x8*)(nxt + ao);
                        al[0][i] = *(const bf16x8*)(nxt + PLANE + ao);
                    }
                }
                if (more) {
                    if (ph == 0)      { stage_round(0, k1, nxt); stage_round(1, k1, nxt); stage_round(2, k1, nxt); }
                    else if (ph == 1) { stage_round(3, k1, nxt); stage_round(4, k1, nxt); }
                    else if (ph == 2) { stage_round(5, k1, nxt); stage_round(6, k1, nxt); }
                    else              { stage_round(7, k1, nxt); }
                }
                __builtin_amdgcn_s_setprio(1);
#pragma unroll
                for (int i = 0; i < 2; ++i)
#pragma unroll
                    for (int j = 0; j < 4; ++j) {
                        f32x4 a = acc[ph * 2 + i][j];
                        a = __builtin_amdgcn_mfma_f32_16x16x32_bf16(ah[ph & 1][i], bfh[j], a, 0, 0, 0);
                        a = __builtin_amdgcn_mfma_f32_16x16x32_bf16(ah[ph & 1][i], bfl[j], a, 0, 0, 0);
                        a = __builtin_amdgcn_mfma_f32_16x16x32_bf16(al[ph & 1][i], bfh[j], a, 0, 0, 0);
                        acc[ph * 2 + i][j] = a;
                    }
                __builtin_amdgcn_s_setprio(0);
                if (ph == 3 && more) {
#pragma unroll
                    for (int j = 0; j < 4; ++j) {
                        const int bo = (wn + j * 16 + l16) * 32 + (quad ^ sw) * 8;
                        bfh[j] = *(const bf16x8*)(nxt + 2 * PLANE + bo);
                        bfl[j] = *(const bf16x8*)(nxt + 3 * PLANE + bo);
                    }
                }
                if (more) {
                    if (ph == 0)      asm volatile("s_waitcnt vmcnt(4)" ::: "memory");
                    else if (ph == 1) asm volatile("s_waitcnt vmcnt(5)" ::: "memory");
                    else              asm volatile("s_waitcnt vmcnt(2)" ::: "memory");
                    asm volatile("s_barrier" ::: "memory");
                    __builtin_amdgcn_sched_barrier(0);
                } else {
                    if (ph == 0) {
                        asm volatile("s_waitcnt vmcnt(1)" ::: "memory");
                        asm volatile("s_barrier" ::: "memory");
                        __builtin_amdgcn_sched_barrier(0);
                    } else if (ph == 1) {
                        asm volatile("s_waitcnt vmcnt(0)" ::: "memory");
                        asm volatile("s_barrier" ::: "memory");
                        __builtin_amdgcn_sched_barrier(0);
                    }
                }
            }
        }
    }

    // --- r11 LDS-bounce epilogue (full-line coalesced stores) ---
    asm volatile("s_barrier" ::: "memory");   // all waves done with tile bufs
    float* strip = (float*)smem + wave * 1024;  // 16x64 f32 private strip
    const float* bz = (z == 1 && bias2) ? bias2 : bias;
#pragma unroll
    for (int i = 0; i < 8; ++i) {
#pragma unroll
        for (int j = 0; j < 4; ++j)
#pragma unroll
            for (int r = 0; r < 4; ++r) {
                const int row = quad * 4 + r;
                const int col = j * 16 + l16;
                strip[row * 64 + (col ^ (row << 2))] = acc[i][j][r];
            }
        asm volatile("s_waitcnt lgkmcnt(0)" ::: "memory");
        __builtin_amdgcn_sched_barrier(0);
#pragma unroll
        for (int k = 0; k < 4; ++k) {
            const int R = k * 4 + (lane >> 4);
            const int c = (lane & 15) * 4;
            f32x4 v = *(const f32x4*)(strip + R * 64 + (c ^ (R << 2)));
            const int grow = m0 + wm + i * 16 + R;
            const int gcol = n0 + wn + c;
            const long long idx = z * sC + (long long)grow * N + gcol;
            if constexpr (OUT == 0) {
                v *= scale;
                *(f32x4*)(Cf + idx) = v;
            } else {
                f32x4 b4 = *(const f32x4*)(bz + gcol);
                v += b4;
                bf16x4 h4, l4;
#pragma unroll
                for (int e = 0; e < 4; ++e) {
                    h4[e] = (bf16_t)v[e];
                    l4[e] = (bf16_t)(v[e] - (float)h4[e]);
                }
                *(bf16x4*)(Ch + idx) = h4;
                *(bf16x4*)(Cl + idx) = l4;
            }
        }
        asm volatile("s_waitcnt lgkmcnt(0)" ::: "memory");
        __builtin_amdgcn_sched_barrier(0);
    }
}

// ---------------------------------------------------------------------------
// Row softmax + dropout, register-resident (r5, verified): S fp32 -> P bf16.
// ---------------------------------------------------------------------------
__global__ __launch_bounds__(256)
void softmax_dropout(const float* __restrict__ S, bf16_t* __restrict__ P) {
    const unsigned row = blockIdx.x;
    const float* rp = S + (long long)row * LSEQ;
    const int tid = threadIdx.x;

    float v[8];
    *(float4*)(v)     = *(const float4*)(rp + tid * 8);
    *(float4*)(v + 4) = *(const float4*)(rp + tid * 8 + 4);

    float m = v[0];
#pragma unroll
    for (int e = 1; e < 8; ++e) m = fmaxf(m, v[e]);
#pragma unroll
    for (int o = 1; o < 64; o <<= 1) m = fmaxf(m, __shfl_xor(m, o));
    __shared__ float redm[4];
    if ((tid & 63) == 0) redm[tid >> 6] = m;
    __syncthreads();
    m = fmaxf(fmaxf(redm[0], redm[1]), fmaxf(redm[2], redm[3]));

    float s = 0.f;
#pragma unroll
    for (int e = 0; e < 8; ++e) { v[e] = __expf(v[e] - m); s += v[e]; }
#pragma unroll
    for (int o = 1; o < 64; o <<= 1) s += __shfl_xor(s, o);
    __shared__ float reds[4];
    if ((tid & 63) == 0) reds[tid >> 6] = s;
    __syncthreads();
    s = (reds[0] + reds[1]) + (reds[2] + reds[3]);

    const float inv = 2.0f / s;  // dropout /0.5 folded in
    const unsigned nb = row * (unsigned)LSEQ + (unsigned)(tid * 8);
    bf16x8 o8;
#pragma unroll
    for (int e = 0; e < 8; ++e)
        o8[e] = (bf16_t)(dropout_keep(nb + e) ? v[e] * inv : 0.0f);
    *(bf16x8*)(P + (long long)row * LSEQ + tid * 8) = o8;
}

// ---------------------------------------------------------------------------
extern "C" void kernel_launch(void* const* d_in, const int* in_sizes, int n_in,
                              void* d_out, int out_size, void* d_ws, size_t ws_size,
                              hipStream_t stream) {
    const float* query = (const float*)d_in[0];
    const float* key_  = (const float*)d_in[1];
    const float* value = (const float*)d_in[2];
    const float* Wq = (const float*)d_in[3];
    const float* bq = (const float*)d_in[4];
    const float* Wk = (const float*)d_in[5];
    const float* bk = (const float*)d_in[6];
    const float* Wv = (const float*)d_in[7];
    const float* bv = (const float*)d_in[8];
    float* out = (float*)d_out;

    // ws layout (bytes), Q1 = 8192*1024*2 = 16.78MB; total 9*Q1 + 8.4MB
    // r11 alias plan:
    //   XvH  @ 0        (Qh region; dead before proj writes Qh)
    //   WvT  @ 2Q1      (Ql region; dead before proj writes Ql)
    //   VT   @ 4Q1
    //   XqkH @ 5Q1, XqkL @ 7Q1 (dead after proj; S overwrites)
    //   WTh/WTl @ 9Q1 (q,k 2-slot)
    //   P = Qh @ 0 (after QK^T)
    char* w = (char*)d_ws;
    const size_t Q1 = (size_t)MROWS * DMODEL * 2;
    const long long DD = (long long)DMODEL * DMODEL;
    bf16_t* Qh  = (bf16_t*)(w);
    bf16_t* Ql  = (bf16_t*)(w + 2 * Q1);
    bf16_t* VT  = (bf16_t*)(w + 4 * Q1);
    float*  S   = (float*)(w + 5 * Q1);
    bf16_t* XvH  = (bf16_t*)(w);                 // aliases Qh
    bf16_t* WvTh = (bf16_t*)(w + 2 * Q1);        // aliases Ql
    bf16_t* WvTl = WvTh + DD;
    bf16_t* XqkH = (bf16_t*)(w + 5 * Q1);
    bf16_t* XqkL = (bf16_t*)(w + 7 * Q1);
    bf16_t* WTh = (bf16_t*)(w + 9 * Q1);
    bf16_t* WTl = (bf16_t*)(w + 9 * Q1 + 2 * (size_t)DMODEL * DMODEL * 2);
    bf16_t* P   = Qh;

    dim3 b256(256);
    dim3 b512(512);
    const int NELEM = MROWS * DMODEL;

    // --- merged prep: all W transposes, all input splits (2 launches)
    split_transpose3<<<dim3(DMODEL / 32, DMODEL / 32, 3), b256, 0, stream>>>(
        Wq, Wk, Wv, WTh, WTl, WvTh, WvTl, DMODEL, DMODEL);
    split_all<<<dim3(NELEM / 1024, 3), b256, 0, stream>>>(
        query, key_, value, XqkH, XqkL, XvH, NELEM);

    // --- V path: V^T = Wv^T @ Xv^T (pipelined plain kernel, row-bias)
    gemm_pipe<2><<<dim3(256), b512, 0, stream>>>(
        WvTh, XvH, bv, nullptr, VT,
        DMODEL, LSEQ, DMODEL, 1.f,
        0, (long long)LSEQ * DMODEL, (long long)DMODEL * LSEQ,
        DMODEL / 128, 4);

    // --- Q and K projections, fused over z
    gemm_mfma_8ph<1><<<dim3(256), b512, 0, stream>>>(
        XqkH, XqkL, WTh, WTl, bq, bk, nullptr, Qh, Ql,
        MROWS, DMODEL, DMODEL, 1.f,
        (long long)NELEM, DD, (long long)NELEM,
        MROWS / 256, 2);

    // --- S = 8 * Q K^T (batched)
    gemm_mfma_8ph<0><<<dim3(256), b512, 0, stream>>>(
        Qh, Ql, Qh + NELEM, Ql + NELEM, nullptr, nullptr, S, nullptr, nullptr,
        LSEQ, LSEQ, DMODEL, SCORE_SCALE,
        (long long)LSEQ * DMODEL, (long long)LSEQ * DMODEL,
        (long long)LSEQ * LSEQ,
        LSEQ / 256, 4);

    // --- softmax + dropout -> P bf16 (aliases Qh region)
    softmax_dropout<<<dim3(MROWS), b256, 0, stream>>>(S, P);

    // --- O = P V (pipelined plain kernel), B operand = V^T [D][LK] per batch
    gemm_pipe<0><<<dim3(256), b512, 0, stream>>>(
        P, VT, nullptr, out, nullptr,
        LSEQ, DMODEL, LSEQ, 1.f,
        (long long)LSEQ * LSEQ, (long long)DMODEL * LSEQ, (long long)LSEQ * DMODEL,
        LSEQ / 128, 4);
}

// Round 7
// 410.219 us; speedup vs baseline: 1.0433x; 1.0433x over previous
//
#include <hip/hip_runtime.h>
#include <math.h>

// Problem constants
#define BATCH  4
#define LSEQ   2048
#define DMODEL 1024
#define MROWS  (BATCH * LSEQ)   // 8192
#define SCORE_SCALE 8.0f        // sqrt(1024/16), reference MULTIPLIES

#define THREEFRY_PARTITIONABLE 1  // verified correct in round 1

typedef __bf16 bf16_t;
typedef bf16_t bf16x8 __attribute__((ext_vector_type(8)));
typedef bf16_t bf16x4 __attribute__((ext_vector_type(4)));
typedef float  f32x4  __attribute__((ext_vector_type(4)));

#define LDSP(p) ((__attribute__((address_space(3))) void*)(p))
#define GLBP(p) ((const __attribute__((address_space(1))) void*)(p))

// ---------------------------------------------------------------------------
// threefry dropout (verified round 1)
// ---------------------------------------------------------------------------
__device__ __forceinline__ unsigned rotl32(unsigned x, int r) {
    return (x << r) | (x >> (32 - r));
}

__device__ __forceinline__ void threefry2x32(unsigned k0, unsigned k1,
                                             unsigned x0, unsigned x1,
                                             unsigned& o0, unsigned& o1) {
    const unsigned ks0 = k0, ks1 = k1, ks2 = k0 ^ k1 ^ 0x1BD11BDAu;
    x0 += ks0; x1 += ks1;
#define TF_R(r) { x0 += x1; x1 = rotl32(x1, r); x1 ^= x0; }
    TF_R(13) TF_R(15) TF_R(26) TF_R(6)
    x0 += ks1; x1 += ks2 + 1u;
    TF_R(17) TF_R(29) TF_R(16) TF_R(24)
    x0 += ks2; x1 += ks0 + 2u;
    TF_R(13) TF_R(15) TF_R(26) TF_R(6)
    x0 += ks0; x1 += ks1 + 3u;
    TF_R(17) TF_R(29) TF_R(16) TF_R(24)
    x0 += ks1; x1 += ks2 + 4u;
    TF_R(13) TF_R(15) TF_R(26) TF_R(6)
    x0 += ks2; x1 += ks0 + 5u;
#undef TF_R
    o0 = x0; o1 = x1;
}

__device__ __forceinline__ bool dropout_keep(unsigned n) {
    unsigned o0, o1;
#if THREEFRY_PARTITIONABLE
    threefry2x32(0u, 42u, 0u, n, o0, o1);
    unsigned bits = o0 ^ o1;
#else
    const unsigned HALF = (unsigned)(BATCH * LSEQ) * (unsigned)LSEQ / 2u;
    unsigned c0 = (n < HALF) ? n : (n - HALF);
    unsigned c1 = (n < HALF) ? (n + HALF) : n;
    threefry2x32(0u, 42u, c0, c1, o0, o1);
    unsigned bits = (n < HALF) ? o0 : o1;
#endif
    return bits < 0x80000000u;
}

// ---------------------------------------------------------------------------
// r11 merged prep kernels (kept).
// split_all: y0=query,y1=key -> hi/lo planes; y2=value -> hi only.
// ---------------------------------------------------------------------------
__global__ __launch_bounds__(256)
void split_all(const float* __restrict__ Xq, const float* __restrict__ Xk,
               const float* __restrict__ Xv,
               bf16_t* __restrict__ hi, bf16_t* __restrict__ lo,
               bf16_t* __restrict__ vh, int n) {
    const int y = blockIdx.y;
    const float* X = (y == 0) ? Xq : (y == 1) ? Xk : Xv;
    long long i = (long long)(blockIdx.x * 256 + threadIdx.x) * 4;
    if (i >= n) return;
    float4 v = *(const float4*)(X + i);
    bf16x4 h, l;
    h[0] = (bf16_t)v.x; l[0] = (bf16_t)(v.x - (float)h[0]);
    h[1] = (bf16_t)v.y; l[1] = (bf16_t)(v.y - (float)h[1]);
    h[2] = (bf16_t)v.z; l[2] = (bf16_t)(v.z - (float)h[2]);
    h[3] = (bf16_t)v.w; l[3] = (bf16_t)(v.w - (float)h[3]);
    if (y < 2) {
        *(bf16x4*)(hi + (long long)y * n + i) = h;
        *(bf16x4*)(lo + (long long)y * n + i) = l;
    } else {
        *(bf16x4*)(vh + i) = h;
    }
}

// W fp32 [K][N] -> W^T hi/lo bf16 [N][K]; z: 0=Wq,1=Wk (2-slot out), 2=Wv (own out)
__global__ __launch_bounds__(256)
void split_transpose3(const float* __restrict__ W0, const float* __restrict__ W1,
                      const float* __restrict__ W2,
                      bf16_t* __restrict__ Th01, bf16_t* __restrict__ Tl01,
                      bf16_t* __restrict__ Thv, bf16_t* __restrict__ Tlv,
                      int Kd, int Nd) {
    __shared__ float t[32][33];
    const int z = blockIdx.z;
    const float* W = (z == 0) ? W0 : (z == 1) ? W1 : W2;
    bf16_t* Th = (z == 2) ? Thv : Th01 + (long long)z * Kd * Nd;
    bf16_t* Tl = (z == 2) ? Tlv : Tl01 + (long long)z * Kd * Nd;
    const int bx = blockIdx.x * 32;  // n
    const int by = blockIdx.y * 32;  // k
    const int tx = threadIdx.x & 31, ty = threadIdx.x >> 5;  // 32x8
#pragma unroll
    for (int i = 0; i < 4; ++i)
        t[ty + i * 8][tx] = W[(long long)(by + ty + i * 8) * Nd + bx + tx];
    __syncthreads();
#pragma unroll
    for (int i = 0; i < 4; ++i) {
        float v = t[tx][ty + i * 8];
        long long idx = (long long)(bx + ty + i * 8) * Kd + by + tx;
        bf16_t h = (bf16_t)v;
        Th[idx] = h;
        Tl[idx] = (bf16_t)(v - (float)h);
    }
}

// ---------------------------------------------------------------------------
// r10/r11 gemm_pipe (kept exactly as benched in r11).
// ---------------------------------------------------------------------------
template <int OUT>
__global__ __launch_bounds__(512, 2)
void gemm_pipe(const bf16_t* __restrict__ A, const bf16_t* __restrict__ B,
               const float* __restrict__ bias,
               float* __restrict__ Cf, bf16_t* __restrict__ Ch,
               int M, int N, int K, float scale,
               long long sA, long long sB, long long sC,
               int NYt, int NZ) {
    constexpr int ABUF = 128 * 32;                 // A plane elements (8 KB)
    constexpr int BUFE = ABUF + 256 * 32;          // one buffer = 24 KB
    __shared__ __align__(16) bf16_t smem[3 * BUFE];  // 72 KB

    const int bid = blockIdx.x;
    const int gid = (bid & 7) * 32 + (bid >> 3);   // 256 blocks
    const int nzy = NZ * NYt;
    const int nx = gid / nzy;
    const int rem = gid - nx * nzy;
    const int zz = rem / NYt;
    const int my = rem - zz * NYt;
    const long long z = zz;
    const int m0 = my * 128, n0 = nx * 256;

    const int tid = threadIdx.x;
    const int lane = tid & 63;
    const int wave = tid >> 6;          // 0..7
    const int quad = lane >> 4;
    const int l16 = lane & 15;
    const int wm = (wave >> 2) * 64;    // 0,64
    const int wn = (wave & 3) * 64;     // 0,64,128,192

    const bf16_t* gA = A + z * sA;
    const bf16_t* gB = B + z * sB;

    const int lrow = lane >> 2;                               // 0..15
    const int scol = ((lane & 3) ^ ((lrow >> 1) & 3)) * 8;    // swizzled col
    const int sw = (l16 >> 1) & 3;                            // read swizzle

    auto stage_tile = [&](int k0, bf16_t* base) {
        {
            const int row = (wave << 4) + lrow;
            __builtin_amdgcn_global_load_lds(
                GLBP(gA + (long long)(m0 + row) * K + k0 + scol),
                LDSP(base + row * 32), 16, 0, 0);
        }
#pragma unroll
        for (int r = 0; r < 2; ++r) {
            const int row = (r << 7) + (wave << 4) + lrow;
            __builtin_amdgcn_global_load_lds(
                GLBP(gB + (long long)(n0 + row) * K + k0 + scol),
                LDSP(base + ABUF + row * 32), 16, 0, 0);
        }
    };

    f32x4 acc[4][4];
#pragma unroll
    for (int i = 0; i < 4; ++i)
#pragma unroll
        for (int j = 0; j < 4; ++j)
            acc[i][j] = (f32x4){0.f, 0.f, 0.f, 0.f};

    bf16x8 fa0[4], fb0[4], fa1[4], fb1[4];

    const int NIT = K >> 5;

    bf16_t* p0 = smem;
    bf16_t* p1 = smem + BUFE;
    bf16_t* p2 = smem + 2 * BUFE;

    stage_tile(0, p0);
    stage_tile(32, p1);
    stage_tile(64, p2);
    asm volatile("s_waitcnt vmcnt(3)" ::: "memory");
    asm volatile("s_barrier" ::: "memory");
    __builtin_amdgcn_sched_barrier(0);
#pragma unroll
    for (int i = 0; i < 4; ++i) {
        const int ao = (wm + i * 16 + l16) * 32 + (quad ^ sw) * 8;
        fa0[i] = *(const bf16x8*)(p0 + ao);
    }
#pragma unroll
    for (int j = 0; j < 4; ++j) {
        const int bo = ABUF + (wn + j * 16 + l16) * 32 + (quad ^ sw) * 8;
        fb0[j] = *(const bf16x8*)(p0 + bo);
    }

#define PIPE_ITER(T, FAc, FBc, FAn, FBn)                                      \
    {                                                                         \
        const int t_ = (T);                                                   \
        if (t_ + 1 < NIT) {                                                   \
            _Pragma("unroll")                                                 \
            for (int i = 0; i < 4; ++i) {                                     \
                const int ao = (wm + i * 16 + l16) * 32 + (quad ^ sw) * 8;    \
                FAn[i] = *(const bf16x8*)(p1 + ao);                           \
            }                                                                 \
            _Pragma("unroll")                                                 \
            for (int j = 0; j < 4; ++j) {                                     \
                const int bo = ABUF + (wn + j * 16 + l16) * 32 + (quad ^ sw) * 8; \
                FBn[j] = *(const bf16x8*)(p1 + bo);                           \
            }                                                                 \
        }                                                                     \
        if (t_ + 3 < NIT) stage_tile((t_ + 3) << 5, p0);                      \
        __builtin_amdgcn_s_setprio(1);                                        \
        _Pragma("unroll")                                                     \
        for (int i = 0; i < 4; ++i)                                           \
            _Pragma("unroll")                                                 \
            for (int j = 0; j < 4; ++j)                                       \
                acc[i][j] = __builtin_amdgcn_mfma_f32_16x16x32_bf16(          \
                    FAc[i], FBc[j], acc[i][j], 0, 0, 0);                      \
        __builtin_amdgcn_s_setprio(0);                                        \
        if (t_ + 2 < NIT) {                                                   \
            asm volatile("s_waitcnt lgkmcnt(0)" ::: "memory");                \
            if (t_ + 3 < NIT) asm volatile("s_waitcnt vmcnt(3)" ::: "memory");\
            else              asm volatile("s_waitcnt vmcnt(0)" ::: "memory");\
            asm volatile("s_barrier" ::: "memory");                           \
            __builtin_amdgcn_sched_barrier(0);                                \
        }                                                                     \
        { bf16_t* tmp_ = p0; p0 = p1; p1 = p2; p2 = tmp_; }                   \
    }

    for (int tp = 0; tp < NIT; tp += 2) {
        PIPE_ITER(tp,     fa0, fb0, fa1, fb1)
        PIPE_ITER(tp + 1, fa1, fb1, fa0, fb0)
    }
#undef PIPE_ITER

    // --- LDS-bounce epilogue (as benched in r11) ---
    asm volatile("s_barrier" ::: "memory");   // all waves done with tile bufs
    float* strip = (float*)smem + wave * 1024;  // 16x64 f32 private strip
#pragma unroll
    for (int i = 0; i < 4; ++i) {
#pragma unroll
        for (int j = 0; j < 4; ++j)
#pragma unroll
            for (int r = 0; r < 4; ++r) {
                const int row = quad * 4 + r;
                const int col = j * 16 + l16;
                strip[row * 64 + (col ^ (row << 2))] = acc[i][j][r];
            }
        asm volatile("s_waitcnt lgkmcnt(0)" ::: "memory");
        __builtin_amdgcn_sched_barrier(0);
#pragma unroll
        for (int k = 0; k < 4; ++k) {
            const int R = k * 4 + (lane >> 4);
            const int c = (lane & 15) * 4;
            f32x4 v = *(const f32x4*)(strip + R * 64 + (c ^ (R << 2)));
            const int grow = m0 + wm + i * 16 + R;
            const int gcol = n0 + wn + c;
            const long long idx = z * sC + (long long)grow * N + gcol;
            if constexpr (OUT == 0) {
                v *= scale;
                *(f32x4*)(Cf + idx) = v;
            } else {
                const float bm = bias[grow];
                v += bm;
                bf16x4 h4;
                h4[0] = (bf16_t)v[0]; h4[1] = (bf16_t)v[1];
                h4[2] = (bf16_t)v[2]; h4[3] = (bf16_t)v[3];
                *(bf16x4*)(Ch + idx) = h4;
            }
        }
        asm volatile("s_waitcnt lgkmcnt(0)" ::: "memory");
        __builtin_amdgcn_sched_barrier(0);
    }
}

// ---------------------------------------------------------------------------
// r9 split kernel, K-loop AND direct-store epilogue (r12: epilogue reverted —
// r11's LDS-bounce added ~14us/dispatch; stores are posted, bounce was pure
// serial overhead. MfmaUtil math confirmed K-loop unchanged: 47*95/109=41).
// ---------------------------------------------------------------------------
template <int OUT>
__global__ __launch_bounds__(512, 2)
void gemm_mfma_8ph(const bf16_t* __restrict__ Ah, const bf16_t* __restrict__ Al,
                   const bf16_t* __restrict__ Bh, const bf16_t* __restrict__ Bl,
                   const float* __restrict__ bias, const float* __restrict__ bias2,
                   float* __restrict__ Cf, bf16_t* __restrict__ Ch,
                   bf16_t* __restrict__ Cl,
                   int M, int N, int K, float scale,
                   long long sA, long long sB, long long sC,
                   int NYt, int NZ) {
    constexpr int TM = 256, TN = 256;
    constexpr int PLANE = 256 * 32;               // elements per plane (16 KB)
    constexpr int HB = 4 * PLANE;                 // half (one buffer) = 64 KB
    __shared__ __align__(16) bf16_t smem[2 * HB]; // 128 KB

    const int bid = blockIdx.x;
    const int gid = (bid & 7) * 32 + (bid >> 3);   // 256 blocks total
    const int nzy = NZ * NYt;
    const int nx = gid / nzy;
    const int rem = gid - nx * nzy;
    const int zz = rem / NYt;
    const int my = rem - zz * NYt;
    const long long z = zz;
    const int m0 = my * TM, n0 = nx * TN;

    const int tid = threadIdx.x;
    const int lane = tid & 63;
    const int wave = tid >> 6;          // 0..7
    const int quad = lane >> 4;
    const int l16 = lane & 15;
    const int wm = (wave >> 2) * 128;   // 0,128
    const int wn = (wave & 3) * 64;     // 0,64,128,192

    const bf16_t* gAh = Ah + z * sA;
    const bf16_t* gAl = Al + z * sA;
    const bf16_t* gBh = Bh + z * sB;
    const bf16_t* gBl = Bl + z * sB;

    const int lrow = lane >> 2;                               // 0..15
    const int scol = ((lane & 3) ^ ((lrow >> 1) & 3)) * 8;    // swizzled col
    const int sw = (l16 >> 1) & 3;                            // read swizzle

    auto stage_round = [&](int r, int k0, bf16_t* base) {
        if (r < 4) {
            const int row = ((r & 1) << 7) + (wave << 4) + lrow;
            const bf16_t* src = (r >= 2) ? gBl : gBh;
            bf16_t* dst = base + ((r >= 2) ? 3 : 2) * PLANE + row * 32;
            __builtin_amdgcn_global_load_lds(
                GLBP(src + (long long)(n0 + row) * K + k0 + scol), LDSP(dst), 16, 0, 0);
        } else {
            const int p = r - 4;
            const int row = (p << 5) + ((wave & 2) ? 128 : 0) + ((wave & 1) << 4) + lrow;
            const bf16_t* src = (wave >= 4) ? gAl : gAh;
            bf16_t* dst = base + ((wave >= 4) ? 1 : 0) * PLANE + row * 32;
            __builtin_amdgcn_global_load_lds(
                GLBP(src + (long long)(m0 + row) * K + k0 + scol), LDSP(dst), 16, 0, 0);
        }
    };

    f32x4 acc[8][4];
#pragma unroll
    for (int i = 0; i < 8; ++i)
#pragma unroll
        for (int j = 0; j < 4; ++j)
            acc[i][j] = (f32x4){0.f, 0.f, 0.f, 0.f};

    bf16x8 ah[2][2], al[2][2];
    bf16x8 bfh[4], bfl[4];

#pragma unroll
    for (int r = 0; r < 8; ++r) stage_round(r, 0, smem);
    asm volatile("s_waitcnt vmcnt(2)" ::: "memory");
    asm volatile("s_barrier" ::: "memory");
    __builtin_amdgcn_sched_barrier(0);
#pragma unroll
    for (int i = 0; i < 2; ++i) {
        const int ao = (wm + i * 16 + l16) * 32 + (quad ^ sw) * 8;
        ah[0][i] = *(const bf16x8*)(smem + ao);
        al[0][i] = *(const bf16x8*)(smem + PLANE + ao);
    }
#pragma unroll
    for (int j = 0; j < 4; ++j) {
        const int bo = (wn + j * 16 + l16) * 32 + (quad ^ sw) * 8;
        bfh[j] = *(const bf16x8*)(smem + 2 * PLANE + bo);
        bfl[j] = *(const bf16x8*)(smem + 3 * PLANE + bo);
    }

    const int NIT = K >> 5;   // 32 (even)
    for (int itp = 0; itp < NIT; itp += 2) {
#pragma unroll
        for (int h = 0; h < 2; ++h) {
            const int it = itp + h;
            const bool more = (it + 1) < NIT;
            const int k1 = (it + 1) << 5;
            bf16_t* cur = smem + h * HB;
            bf16_t* nxt = smem + (h ^ 1) * HB;
#pragma unroll
            for (int ph = 0; ph < 4; ++ph) {
                if (ph < 3) {
#pragma unroll
                    for (int i = 0; i < 2; ++i) {
                        const int ao = (wm + ((ph + 1) * 2 + i) * 16 + l16) * 32 + (quad ^ sw) * 8;
                        ah[(ph + 1) & 1][i] = *(const bf16x8*)(cur + ao);
                        al[(ph + 1) & 1][i] = *(const bf16x8*)(cur + PLANE + ao);
                    }
                } else if (more) {
#pragma unroll
                    for (int i = 0; i < 2; ++i) {
                        const int ao = (wm + i * 16 + l16) * 32 + (quad ^ sw) * 8;
                        ah[0][i] = *(const bf16x8*)(nxt + ao);
                        al[0][i] = *(const bf16x8*)(nxt + PLANE + ao);
                    }
                }
                if (more) {
                    if (ph == 0)      { stage_round(0, k1, nxt); stage_round(1, k1, nxt); stage_round(2, k1, nxt); }
                    else if (ph == 1) { stage_round(3, k1, nxt); stage_round(4, k1, nxt); }
                    else if (ph == 2) { stage_round(5, k1, nxt); stage_round(6, k1, nxt); }
                    else              { stage_round(7, k1, nxt); }
                }
                __builtin_amdgcn_s_setprio(1);
#pragma unroll
                for (int i = 0; i < 2; ++i)
#pragma unroll
                    for (int j = 0; j < 4; ++j) {
                        f32x4 a = acc[ph * 2 + i][j];
                        a = __builtin_amdgcn_mfma_f32_16x16x32_bf16(ah[ph & 1][i], bfh[j], a, 0, 0, 0);
                        a = __builtin_amdgcn_mfma_f32_16x16x32_bf16(ah[ph & 1][i], bfl[j], a, 0, 0, 0);
                        a = __builtin_amdgcn_mfma_f32_16x16x32_bf16(al[ph & 1][i], bfh[j], a, 0, 0, 0);
                        acc[ph * 2 + i][j] = a;
                    }
                __builtin_amdgcn_s_setprio(0);
                if (ph == 3 && more) {
#pragma unroll
                    for (int j = 0; j < 4; ++j) {
                        const int bo = (wn + j * 16 + l16) * 32 + (quad ^ sw) * 8;
                        bfh[j] = *(const bf16x8*)(nxt + 2 * PLANE + bo);
                        bfl[j] = *(const bf16x8*)(nxt + 3 * PLANE + bo);
                    }
                }
                if (more) {
                    if (ph == 0)      asm volatile("s_waitcnt vmcnt(4)" ::: "memory");
                    else if (ph == 1) asm volatile("s_waitcnt vmcnt(5)" ::: "memory");
                    else              asm volatile("s_waitcnt vmcnt(2)" ::: "memory");
                    asm volatile("s_barrier" ::: "memory");
                    __builtin_amdgcn_sched_barrier(0);
                } else {
                    if (ph == 0) {
                        asm volatile("s_waitcnt vmcnt(1)" ::: "memory");
                        asm volatile("s_barrier" ::: "memory");
                        __builtin_amdgcn_sched_barrier(0);
                    } else if (ph == 1) {
                        asm volatile("s_waitcnt vmcnt(0)" ::: "memory");
                        asm volatile("s_barrier" ::: "memory");
                        __builtin_amdgcn_sched_barrier(0);
                    }
                }
            }
        }
    }

    // --- direct-store epilogue (r9, verified 94.8us; stores are posted) ---
    const float* bz = (z == 1 && bias2) ? bias2 : bias;
#pragma unroll
    for (int i = 0; i < 8; ++i)
#pragma unroll
        for (int j = 0; j < 4; ++j) {
            const int n = n0 + wn + j * 16 + l16;
            float bvn = 0.f;
            if constexpr (OUT != 0) bvn = bz[n];
#pragma unroll
            for (int r = 0; r < 4; ++r) {
                const int m = m0 + wm + i * 16 + quad * 4 + r;
                const long long idx = z * sC + (long long)m * N + n;
                float v = acc[i][j][r];
                if constexpr (OUT == 0) {
                    Cf[idx] = v * scale;
                } else {
                    v += bvn;
                    bf16_t h = (bf16_t)v;
                    Ch[idx] = h;
                    Cl[idx] = (bf16_t)(v - (float)h);
                }
            }
        }
}

// ---------------------------------------------------------------------------
// Row softmax + dropout, register-resident (r5, verified): S fp32 -> P bf16.
// ---------------------------------------------------------------------------
__global__ __launch_bounds__(256)
void softmax_dropout(const float* __restrict__ S, bf16_t* __restrict__ P) {
    const unsigned row = blockIdx.x;
    const float* rp = S + (long long)row * LSEQ;
    const int tid = threadIdx.x;

    float v[8];
    *(float4*)(v)     = *(const float4*)(rp + tid * 8);
    *(float4*)(v + 4) = *(const float4*)(rp + tid * 8 + 4);

    float m = v[0];
#pragma unroll
    for (int e = 1; e < 8; ++e) m = fmaxf(m, v[e]);
#pragma unroll
    for (int o = 1; o < 64; o <<= 1) m = fmaxf(m, __shfl_xor(m, o));
    __shared__ float redm[4];
    if ((tid & 63) == 0) redm[tid >> 6] = m;
    __syncthreads();
    m = fmaxf(fmaxf(redm[0], redm[1]), fmaxf(redm[2], redm[3]));

    float s = 0.f;
#pragma unroll
    for (int e = 0; e < 8; ++e) { v[e] = __expf(v[e] - m); s += v[e]; }
#pragma unroll
    for (int o = 1; o < 64; o <<= 1) s += __shfl_xor(s, o);
    __shared__ float reds[4];
    if ((tid & 63) == 0) reds[tid >> 6] = s;
    __syncthreads();
    s = (reds[0] + reds[1]) + (reds[2] + reds[3]);

    const float inv = 2.0f / s;  // dropout /0.5 folded in
    const unsigned nb = row * (unsigned)LSEQ + (unsigned)(tid * 8);
    bf16x8 o8;
#pragma unroll
    for (int e = 0; e < 8; ++e)
        o8[e] = (bf16_t)(dropout_keep(nb + e) ? v[e] * inv : 0.0f);
    *(bf16x8*)(P + (long long)row * LSEQ + tid * 8) = o8;
}

// ---------------------------------------------------------------------------
extern "C" void kernel_launch(void* const* d_in, const int* in_sizes, int n_in,
                              void* d_out, int out_size, void* d_ws, size_t ws_size,
                              hipStream_t stream) {
    const float* query = (const float*)d_in[0];
    const float* key_  = (const float*)d_in[1];
    const float* value = (const float*)d_in[2];
    const float* Wq = (const float*)d_in[3];
    const float* bq = (const float*)d_in[4];
    const float* Wk = (const float*)d_in[5];
    const float* bk = (const float*)d_in[6];
    const float* Wv = (const float*)d_in[7];
    const float* bv = (const float*)d_in[8];
    float* out = (float*)d_out;

    // ws layout (bytes), Q1 = 8192*1024*2 = 16.78MB
    // alias plan (r11, kept):
    //   XvH  @ 0        (Qh region; dead before proj writes Qh)
    //   WvT  @ 2Q1      (Ql region; dead before proj writes Ql)
    //   VT   @ 4Q1
    //   XqkH @ 5Q1, XqkL @ 7Q1 (dead after proj; S overwrites)
    //   WTh/WTl @ 9Q1 (q,k 2-slot)
    //   P = Qh @ 0 (after QK^T)
    char* w = (char*)d_ws;
    const size_t Q1 = (size_t)MROWS * DMODEL * 2;
    const long long DD = (long long)DMODEL * DMODEL;
    bf16_t* Qh  = (bf16_t*)(w);
    bf16_t* Ql  = (bf16_t*)(w + 2 * Q1);
    bf16_t* VT  = (bf16_t*)(w + 4 * Q1);
    float*  S   = (float*)(w + 5 * Q1);
    bf16_t* XvH  = (bf16_t*)(w);                 // aliases Qh
    bf16_t* WvTh = (bf16_t*)(w + 2 * Q1);        // aliases Ql
    bf16_t* WvTl = WvTh + DD;
    bf16_t* XqkH = (bf16_t*)(w + 5 * Q1);
    bf16_t* XqkL = (bf16_t*)(w + 7 * Q1);
    bf16_t* WTh = (bf16_t*)(w + 9 * Q1);
    bf16_t* WTl = (bf16_t*)(w + 9 * Q1 + 2 * (size_t)DMODEL * DMODEL * 2);
    bf16_t* P   = Qh;

    dim3 b256(256);
    dim3 b512(512);
    const int NELEM = MROWS * DMODEL;

    // --- merged prep: all W transposes, all input splits (2 launches)
    split_transpose3<<<dim3(DMODEL / 32, DMODEL / 32, 3), b256, 0, stream>>>(
        Wq, Wk, Wv, WTh, WTl, WvTh, WvTl, DMODEL, DMODEL);
    split_all<<<dim3(NELEM / 1024, 3), b256, 0, stream>>>(
        query, key_, value, XqkH, XqkL, XvH, NELEM);

    // --- V path: V^T = Wv^T @ Xv^T (pipelined plain kernel, row-bias)
    gemm_pipe<2><<<dim3(256), b512, 0, stream>>>(
        WvTh, XvH, bv, nullptr, VT,
        DMODEL, LSEQ, DMODEL, 1.f,
        0, (long long)LSEQ * DMODEL, (long long)DMODEL * LSEQ,
        DMODEL / 128, 4);

    // --- Q and K projections, fused over z
    gemm_mfma_8ph<1><<<dim3(256), b512, 0, stream>>>(
        XqkH, XqkL, WTh, WTl, bq, bk, nullptr, Qh, Ql,
        MROWS, DMODEL, DMODEL, 1.f,
        (long long)NELEM, DD, (long long)NELEM,
        MROWS / 256, 2);

    // --- S = 8 * Q K^T (batched)
    gemm_mfma_8ph<0><<<dim3(256), b512, 0, stream>>>(
        Qh, Ql, Qh + NELEM, Ql + NELEM, nullptr, nullptr, S, nullptr, nullptr,
        LSEQ, LSEQ, DMODEL, SCORE_SCALE,
        (long long)LSEQ * DMODEL, (long long)LSEQ * DMODEL,
        (long long)LSEQ * LSEQ,
        LSEQ / 256, 4);

    // --- softmax + dropout -> P bf16 (aliases Qh region)
    softmax_dropout<<<dim3(MROWS), b256, 0, stream>>>(S, P);

    // --- O = P V (pipelined plain kernel), B operand = V^T [D][LK] per batch
    gemm_pipe<0><<<dim3(256), b512, 0, stream>>>(
        P, VT, nullptr, out, nullptr,
        LSEQ, DMODEL, LSEQ, 1.f,
        (long long)LSEQ * LSEQ, (long long)DMODEL * LSEQ, (long long)LSEQ * DMODEL,
        LSEQ / 128, 4);
}